// Round 2
// baseline (288.009 us; speedup 1.0000x reference)
//
#include <hip/hip_runtime.h>

#define B_ 32
#define C_ 64
#define N_ 1024
#define T_ 64

typedef __attribute__((ext_vector_type(8))) _Float16 half8;   // 8 f16 = 4 VGPR
typedef __attribute__((ext_vector_type(4))) _Float16 half4;
typedef __attribute__((ext_vector_type(4))) float f32x4;

// ---------------------------------------------------------------------------
// R16: fused producer/consumer pipeline. Serial K1->K2 forfeited read/write
// overlap (K1 85us read-bound + K2 ~40us; mixed roofline for 648 MB ~100us).
// 512 blocks x 512 thr, all co-resident (2/CU). Odd slots produce q (K1 math,
// 32-row chunks, NT reads); even slots consume (R15 K2 body per 32-row tile),
// gated by per-batch device-scope flags. Batch<->XCD alignment via bid&7.
// ---------------------------------------------------------------------------

__global__ void k_init(int* flags) {
    if (threadIdx.x < 32) flags[threadIdx.x] = 0;
}

__global__ __launch_bounds__(512, 4) void k_fused(
        const float* __restrict__ x,
        const float* __restrict__ W,
        const float* __restrict__ alpha,
        float* __restrict__ out,
        _Float16* __restrict__ q_h,
        int* __restrict__ flags) {
    const int u    = blockIdx.x;
    const int xcd  = u & 7;          // XCD under round-robin dispatch
    const int slot = u >> 3;         // 0..63
    const int role = slot & 1;       // 1 = producer (q), 0 = consumer (scores)
    const int m    = slot >> 1;      // 0..31
    const int tid  = threadIdx.x;

    __shared__ float Ws[T_][T_];                    // 16 KB fp32 W
    __shared__ _Float16 qwh[32][72];                // 4.5 KB f16 qw tile
    __shared__ float red[32][8];                    // 1 KB

    if (role) {
        // ================= PRODUCER: q rows m*32..m*32+31 of batch g*8+xcd ==
        const int nr = m * 32;
#pragma unroll 1
        for (int g = 0; g < 4; ++g) {
            const int b = g * 8 + xcd;
            const float* xb = x + (size_t)b * C_ * N_ * T_ + (size_t)nr * T_;
            f32x4 acc = {0.f, 0.f, 0.f, 0.f};
#pragma unroll 8
            for (int c = 0; c < C_; ++c) {
                f32x4 v = __builtin_nontemporal_load(
                    (const f32x4*)(xb + (size_t)c * N_ * T_) + tid);
                const float ac = alpha[c];
                acc[0] += ac * v[0]; acc[1] += ac * v[1];
                acc[2] += ac * v[2]; acc[3] += ac * v[3];
            }
            half4 h;
#pragma unroll
            for (int j = 0; j < 4; ++j) h[j] = (_Float16)acc[j];   // RTNE cvt
            *(half4*)(q_h + ((size_t)b * N_ + nr) * T_ + (size_t)tid * 4) = h;

            __syncthreads();            // all waves' stores drained (vmcnt(0) pre-barrier)
            if (tid == 0) {
                __threadfence();        // wbl2: q_h visible device-wide (cross-XCD)
                __hip_atomic_fetch_add(&flags[g * 8 + xcd], 1,
                                       __ATOMIC_RELEASE, __HIP_MEMORY_SCOPE_AGENT);
            }
        }
        return;                         // frees CU slots for consumer tail
    }

    // ================= CONSUMER: tile (b = g*8+xcd, rows m*32..+31) =========
    const int w    = tid >> 6;          // wave 0..7 -> cols w*128
    const int lane = tid & 63;
    const int lr   = lane & 15;
    const int lk   = lane >> 4;
    const int n0   = m * 32;

    // ---- stage W once (fp32, coalesced) ----
    {
        const f32x4* Wv = (const f32x4*)W;
        f32x4* Wd = (f32x4*)&Ws[0][0];
        Wd[tid]       = Wv[tid];
        Wd[tid + 512] = Wv[tid + 512];
    }
    __syncthreads();

#pragma unroll 1
    for (int g = 0; g < 4; ++g) {
        const int b = g * 8 + xcd;

        // ---- wait for q-plane of batch b ----
        if (tid == 0) {
            while (__hip_atomic_load(&flags[g * 8 + xcd], __ATOMIC_RELAXED,
                                     __HIP_MEMORY_SCOPE_AGENT) < 32)
                __builtin_amdgcn_s_sleep(8);
            __threadfence();            // inv: subsequent q_h reads see fresh data
        }
        __syncthreads();

        // ---- qw tile = q @ W via MFMA, split-precision W (hi+lo f16) ----
        {
            const int tr = w >> 2, tc = w & 3;
            const size_t ar = ((size_t)b * N_ + n0 + tr * 16 + lr) * T_ + lk * 8;
            half8 a0 = *(const half8*)(q_h + ar);
            half8 a1 = *(const half8*)(q_h + ar + 32);
            half8 bh0, bh1, bl0, bl1;
#pragma unroll
            for (int j = 0; j < 8; ++j) {
                const float wv0 = Ws[lk * 8 + j][tc * 16 + lr];
                const float wv1 = Ws[lk * 8 + 32 + j][tc * 16 + lr];
                const _Float16 h0 = (_Float16)wv0;
                const _Float16 h1 = (_Float16)wv1;
                bh0[j] = h0; bl0[j] = (_Float16)(wv0 - (float)h0);
                bh1[j] = h1; bl1[j] = (_Float16)(wv1 - (float)h1);
            }
            f32x4 a = {0.f, 0.f, 0.f, 0.f};
            a = __builtin_amdgcn_mfma_f32_16x16x32_f16(a0, bh0, a, 0, 0, 0);
            a = __builtin_amdgcn_mfma_f32_16x16x32_f16(a1, bh1, a, 0, 0, 0);
            a = __builtin_amdgcn_mfma_f32_16x16x32_f16(a0, bl0, a, 0, 0, 0);
            a = __builtin_amdgcn_mfma_f32_16x16x32_f16(a1, bl1, a, 0, 0, 0);
#pragma unroll
            for (int r = 0; r < 4; ++r)
                qwh[tr * 16 + lk * 4 + r][tc * 16 + lr] = (_Float16)a[r];
        }
        __syncthreads();

        // ---- hoist A-frags to registers ----
        half8 af[2][2];
#pragma unroll
        for (int gg = 0; gg < 2; ++gg) {
            af[gg][0] = *(const half8*)&qwh[gg * 16 + lr][lk * 8];
            af[gg][1] = *(const half8*)&qwh[gg * 16 + lr][lk * 8 + 32];
        }

        // ---- main MFMA loop: 2 f16 MFMAs/tile, 2-deep B prefetch ----
        f32x4 acc[2][8];
#pragma unroll
        for (int gg = 0; gg < 2; ++gg)
#pragma unroll
            for (int cf = 0; cf < 8; ++cf) acc[gg][cf] = {0.f, 0.f, 0.f, 0.f};

        const size_t cb0 = ((size_t)b * N_ + w * 128 + lr) * T_ + lk * 8;
        half8 pb0 = *(const half8*)(q_h + cb0);
        half8 pb1 = *(const half8*)(q_h + cb0 + 32);
#pragma unroll
        for (int cf = 0; cf < 8; ++cf) {
            const half8 bh0 = pb0;
            const half8 bh1 = pb1;
            if (cf < 7) {
                const size_t cbn = cb0 + (size_t)(cf + 1) * 16 * T_;
                pb0 = *(const half8*)(q_h + cbn);
                pb1 = *(const half8*)(q_h + cbn + 32);
            }
#pragma unroll
            for (int gg = 0; gg < 2; ++gg) {
                f32x4 a = acc[gg][cf];
                a = __builtin_amdgcn_mfma_f32_16x16x32_f16(af[gg][0], bh0, a, 0, 0, 0);
                a = __builtin_amdgcn_mfma_f32_16x16x32_f16(af[gg][1], bh1, a, 0, 0, 0);
                acc[gg][cf] = a;
            }
        }

        // ---- max-free softmax epilogue ----
        float sv[2][4];
#pragma unroll
        for (int gg = 0; gg < 2; ++gg) {
#pragma unroll
            for (int r = 0; r < 4; ++r) {
                float ssum = 0.f;
#pragma unroll
                for (int cf = 0; cf < 8; ++cf) {
                    float e = __expf(acc[gg][cf][r]);
                    acc[gg][cf][r] = e;
                    ssum += e;
                }
                ssum += __shfl_xor(ssum, 1);
                ssum += __shfl_xor(ssum, 2);
                ssum += __shfl_xor(ssum, 4);
                ssum += __shfl_xor(ssum, 8);
                sv[gg][r] = ssum;
            }
            if (lr == 0) {
#pragma unroll
                for (int r = 0; r < 4; ++r)
                    red[gg * 16 + lk * 4 + r][w] = sv[gg][r];
            }
        }
        __syncthreads();

#pragma unroll
        for (int gg = 0; gg < 2; ++gg) {
#pragma unroll
            for (int r = 0; r < 4; ++r) {
                f32x4 p0 = *(f32x4*)&red[gg * 16 + lk * 4 + r][0];
                f32x4 p1 = *(f32x4*)&red[gg * 16 + lk * 4 + r][4];
                const float inv = 1.0f / (p0[0] + p0[1] + p0[2] + p0[3] +
                                          p1[0] + p1[1] + p1[2] + p1[3]);
                float* orow = out + ((size_t)b * N_ + n0 + gg * 16 + lk * 4 + r) * N_
                                  + w * 128 + lr;
#pragma unroll
                for (int cf = 0; cf < 8; ++cf)
                    orow[cf * 16] = acc[gg][cf][r] * inv;
            }
        }
        __syncthreads();   // red/qwh safe to reuse next group
    }
}

// ---------------------------------------------------------------------------
extern "C" void kernel_launch(void* const* d_in, const int* in_sizes, int n_in,
                              void* d_out, int out_size, void* d_ws, size_t ws_size,
                              hipStream_t stream) {
    const float* x     = (const float*)d_in[0];
    const float* W     = (const float*)d_in[1];
    const float* alpha = (const float*)d_in[2];
    float* out = (float*)d_out;

    _Float16* q_h = (_Float16*)d_ws;                         // [B,N,T] f16, 4 MB
    int* flags    = (int*)((char*)d_ws + (4u << 20));        // 32 ints

    k_init<<<1, 32, 0, stream>>>(flags);
    k_fused<<<512, 512, 0, stream>>>(x, W, alpha, out, q_h, flags);
}

// Round 3
// 124.494 us; speedup vs baseline: 2.3134x; 2.3134x over previous
//
#include <hip/hip_runtime.h>

#define B_ 32
#define C_ 64
#define N_ 1024
#define T_ 64

typedef __attribute__((ext_vector_type(8))) _Float16 half8;   // 8 f16 = 4 VGPR
typedef __attribute__((ext_vector_type(4))) _Float16 half4;
typedef __attribute__((ext_vector_type(4))) float f32x4;

// ---------------------------------------------------------------------------
// K1: q = sum_c alpha[c]*x[b,c,:,:], stored as ONE fp16 plane. Pure stream,
// NT loads on x (read-once), 95% read ceiling (R8 probe) — do not touch.
// ---------------------------------------------------------------------------
__global__ __launch_bounds__(256) void k_q(const float* __restrict__ x,
                                           const float* __restrict__ alpha,
                                           _Float16* __restrict__ q_h) {
    const int bid = blockIdx.x;
    const int s1  = (bid & 7) * 256 + (bid >> 3);   // bijective, 2048%8==0
    const int b   = s1 >> 6;
    const int n0  = (s1 & 63) * 16;
    const int tid = threadIdx.x;

    const f32x4* xb = (const f32x4*)(x + (size_t)b * C_ * N_ * T_
                                       + (size_t)n0 * T_);
    f32x4 acc = {0.f, 0.f, 0.f, 0.f};
#pragma unroll 4
    for (int c = 0; c < C_; ++c) {
        f32x4 v = __builtin_nontemporal_load(&xb[(size_t)c * (N_ * T_ / 4) + tid]);
        const float ac = alpha[c];
        acc[0] += ac * v[0]; acc[1] += ac * v[1];
        acc[2] += ac * v[2]; acc[3] += ac * v[3];
    }

    half4 h;
#pragma unroll
    for (int j = 0; j < 4; ++j) h[j] = (_Float16)acc[j];   // RTNE cvt
    *(half4*)(q_h + ((size_t)b * N_ + n0) * T_ + (size_t)tid * 4) = h;
}

// ---------------------------------------------------------------------------
// K2 (R17): R15 body, ONE change — MFMA operands SWAPPED in the main loop so
// the output tile comes out transposed in-register:
//   mfma(stripe, tile): D[row=lk*4+r][col=lr] -> score[n0+g*16+lr (out ROW)]
//                                                     [w*128+cf*16+lk*4+r (COL)]
// Each lane then owns ONE out row per g with f32x4 = 4 CONSECUTIVE cols:
//  - stores become global_store_dwordx4 (16 per thread, was 64 scalar dword)
//  - softmax row-sum: 31 adds + 2 shfl_xor (was 4 rows x 4 shfl each)
// All operand loads unchanged (A/B fragment layouts are symmetric).
// Theory: K2's 40us (vs 19us write floor) is store-issue/segment-bound
// (NT-policy and LDS-issue theories falsified R14/R15; fusion falsified R16).
// Predict K2 ~26us, total ~111us. If unchanged -> hidden RFO traffic, next
// step is LDS-transpose epilogue.
// ---------------------------------------------------------------------------
__global__ __launch_bounds__(512, 4) void k_scores_softmax(
        const _Float16* __restrict__ q_h,
        const float* __restrict__ W,
        float* __restrict__ out) {
    const int bid = blockIdx.x;
    const int s   = (bid & 7) * 128 + (bid >> 3);   // bijective, 1024%8==0
    const int b   = s >> 5;
    const int n0  = (s & 31) * 32;
    const int tid  = threadIdx.x;
    const int w    = tid >> 6;                      // wave 0..7 -> cols w*128
    const int lane = tid & 63;
    const int lr   = lane & 15;
    const int lk   = lane >> 4;

    __shared__ float Ws[T_][T_];                    // 16 KB fp32 W
    __shared__ _Float16 qwh[32][72];                // 4.5 KB f16 qw tile
    __shared__ float red[32][8];                    // 1 KB

    // ---- stage W (fp32, coalesced — proven pattern) ----
    {
        const f32x4* Wv = (const f32x4*)W;
        f32x4* Wd = (f32x4*)&Ws[0][0];
        Wd[tid]       = Wv[tid];
        Wd[tid + 512] = Wv[tid + 512];
    }
    __syncthreads();

    // ---- qw tile = q @ W via MFMA, split-precision W (hi+lo f16) ----
    // wave w computes 16x16 tile (tr = w>>2 row-block, tc = w&3 col-block)
    {
        const int tr = w >> 2, tc = w & 3;
        const size_t ar = ((size_t)b * N_ + n0 + tr * 16 + lr) * T_ + lk * 8;
        half8 a0 = *(const half8*)(q_h + ar);        // k = lk*8 .. +7
        half8 a1 = *(const half8*)(q_h + ar + 32);   // k = 32+lk*8 .. +7
        half8 bh0, bh1, bl0, bl1;
#pragma unroll
        for (int j = 0; j < 8; ++j) {
            const float wv0 = Ws[lk * 8 + j][tc * 16 + lr];
            const float wv1 = Ws[lk * 8 + 32 + j][tc * 16 + lr];
            const _Float16 h0 = (_Float16)wv0;
            const _Float16 h1 = (_Float16)wv1;
            bh0[j] = h0; bl0[j] = (_Float16)(wv0 - (float)h0);
            bh1[j] = h1; bl1[j] = (_Float16)(wv1 - (float)h1);
        }
        f32x4 a = {0.f, 0.f, 0.f, 0.f};
        a = __builtin_amdgcn_mfma_f32_16x16x32_f16(a0, bh0, a, 0, 0, 0);
        a = __builtin_amdgcn_mfma_f32_16x16x32_f16(a1, bh1, a, 0, 0, 0);
        a = __builtin_amdgcn_mfma_f32_16x16x32_f16(a0, bl0, a, 0, 0, 0);
        a = __builtin_amdgcn_mfma_f32_16x16x32_f16(a1, bl1, a, 0, 0, 0);
        // C layout: col = lr, row = lk*4 + r
#pragma unroll
        for (int r = 0; r < 4; ++r)
            qwh[tr * 16 + lk * 4 + r][tc * 16 + lr] = (_Float16)a[r];
    }
    __syncthreads();

    // ---- hoist A-frags (qw tile rows) to registers ONCE ----
    half8 af[2][2];
#pragma unroll
    for (int g = 0; g < 2; ++g) {
        af[g][0] = *(const half8*)&qwh[g * 16 + lr][lk * 8];
        af[g][1] = *(const half8*)&qwh[g * 16 + lr][lk * 8 + 32];
    }

    // ---- main MFMA loop: SWAPPED operands -> transposed output tile ----
    f32x4 acc[2][8];
#pragma unroll
    for (int g = 0; g < 2; ++g)
#pragma unroll
        for (int cf = 0; cf < 8; ++cf) acc[g][cf] = {0.f, 0.f, 0.f, 0.f};

    const size_t cb0 = ((size_t)b * N_ + w * 128 + lr) * T_ + lk * 8;
    half8 pb0 = *(const half8*)(q_h + cb0);
    half8 pb1 = *(const half8*)(q_h + cb0 + 32);
#pragma unroll
    for (int cf = 0; cf < 8; ++cf) {
        const half8 bh0 = pb0;
        const half8 bh1 = pb1;
        if (cf < 7) {
            const size_t cbn = cb0 + (size_t)(cf + 1) * 16 * T_;
            pb0 = *(const half8*)(q_h + cbn);
            pb1 = *(const half8*)(q_h + cbn + 32);
        }
#pragma unroll
        for (int g = 0; g < 2; ++g) {
            f32x4 a = acc[g][cf];
            // swapped: stripe as A, tile as B -> lane owns row n0+g*16+lr,
            // reg r = col w*128+cf*16+lk*4+r (4 consecutive floats!)
            a = __builtin_amdgcn_mfma_f32_16x16x32_f16(bh0, af[g][0], a, 0, 0, 0);
            a = __builtin_amdgcn_mfma_f32_16x16x32_f16(bh1, af[g][1], a, 0, 0, 0);
            acc[g][cf] = a;
        }
    }

    // ---- max-free softmax epilogue, ONE barrier ----
    // acc[g][cf][r] = score[n0 + g*16 + lr][w*128 + cf*16 + lk*4 + r]
#pragma unroll
    for (int g = 0; g < 2; ++g) {
        float ssum = 0.f;
#pragma unroll
        for (int cf = 0; cf < 8; ++cf) {
#pragma unroll
            for (int r = 0; r < 4; ++r) {
                float e = __expf(acc[g][cf][r]);
                acc[g][cf][r] = e;
                ssum += e;
            }
        }
        // combine the 4 lanes (lk=0..3) sharing this row
        ssum += __shfl_xor(ssum, 16);
        ssum += __shfl_xor(ssum, 32);
        if (lane < 16) red[g * 16 + lr][w] = ssum;
    }
    __syncthreads();

#pragma unroll
    for (int g = 0; g < 2; ++g) {
        f32x4 p0 = *(f32x4*)&red[g * 16 + lr][0];
        f32x4 p1 = *(f32x4*)&red[g * 16 + lr][4];
        const float inv = 1.0f / (p0[0] + p0[1] + p0[2] + p0[3] +
                                  p1[0] + p1[1] + p1[2] + p1[3]);
        f32x4* orow = (f32x4*)(out + ((size_t)b * N_ + n0 + g * 16 + lr) * N_
                                   + w * 128 + lk * 4);
#pragma unroll
        for (int cf = 0; cf < 8; ++cf) {
            f32x4 v = acc[g][cf];
            v[0] *= inv; v[1] *= inv; v[2] *= inv; v[3] *= inv;
            orow[cf * 4] = v;                       // dwordx4, 16 B/lane
        }
    }
}

// ---------------------------------------------------------------------------
extern "C" void kernel_launch(void* const* d_in, const int* in_sizes, int n_in,
                              void* d_out, int out_size, void* d_ws, size_t ws_size,
                              hipStream_t stream) {
    const float* x     = (const float*)d_in[0];
    const float* W     = (const float*)d_in[1];
    const float* alpha = (const float*)d_in[2];
    float* out = (float*)d_out;

    _Float16* q_h = (_Float16*)d_ws;                // [B,N,T] f16, 4 MB

    k_q<<<2048, 256, 0, stream>>>(x, alpha, q_h);
    k_scores_softmax<<<1024, 512, 0, stream>>>(q_h, W, out);
}